// Round 2
// baseline (490.466 us; speedup 1.0000x reference)
//
#include <hip/hip_runtime.h>
#include <math.h>

#define BB 64
#define TT 1000
#define VV 512
#define LL 256
#define SS 513           // 2*LL+1
#define NEGV (-1e30f)
#define DEPTH 8

// ---------------------------------------------------------------------------
// Kernel 1: lse[b*T+t] = logsumexp over V of logits[b,t,:]
// One wave (64 lanes) per row; 4 rows per 256-thread block.
// ---------------------------------------------------------------------------
__global__ __launch_bounds__(256) void ctc_lse_kernel(
    const float* __restrict__ logits, float* __restrict__ lse) {
  int wave = threadIdx.x >> 6;
  int lane = threadIdx.x & 63;
  int row  = blockIdx.x * 4 + wave;          // rows = BB*TT = 64000 exactly
  const float4* p = (const float4*)(logits + (size_t)row * VV);
  float4 a = p[lane];
  float4 b = p[lane + 64];
  float m = fmaxf(fmaxf(fmaxf(a.x, a.y), fmaxf(a.z, a.w)),
                  fmaxf(fmaxf(b.x, b.y), fmaxf(b.z, b.w)));
  #pragma unroll
  for (int off = 32; off; off >>= 1) m = fmaxf(m, __shfl_xor(m, off, 64));
  float s = __expf(a.x - m) + __expf(a.y - m) + __expf(a.z - m) + __expf(a.w - m)
          + __expf(b.x - m) + __expf(b.y - m) + __expf(b.z - m) + __expf(b.w - m);
  #pragma unroll
  for (int off = 32; off; off >>= 1) s += __shfl_xor(s, off, 64);
  if (lane == 0) lse[row] = m + __logf(s);
}

// ---------------------------------------------------------------------------
// Kernel 2: CTC forward DP. One block per batch element, 512 threads.
// Thread tid handles extended state s = tid; thread 0 additionally s = 512.
// alpha double-buffered in LDS; one barrier per timestep.
// DEPTH-deep register prefetch of per-thread gathered logit + row lse.
// ---------------------------------------------------------------------------
__global__ __launch_bounds__(512) void ctc_dp_kernel(
    const float* __restrict__ logits, const int* __restrict__ labels,
    const float* __restrict__ lse, float* __restrict__ out) {
  __shared__ float alpha[2][SS];
  __shared__ int nzcnt[4];

  const int b   = blockIdx.x;
  const int tid = threadIdx.x;
  const int* lab = labels + b * LL;

  // ---- label length: popcount of nonzero labels (first 4 waves) ----
  if (tid < 256) {
    bool nz = (lab[tid] != 0);
    unsigned long long mask = __ballot(nz);
    if ((tid & 63) == 0) nzcnt[tid >> 6] = __popcll(mask);
  }

  // ---- per-thread symbol & skip-transition setup ----
  int sym;  bool skip;
  if (tid & 1) {
    int k  = tid >> 1;             // label index 0..255
    int v  = lab[k];
    int vp = (k > 0) ? lab[k - 1] : 0;
    sym  = v;
    skip = (v != 0) && (k > 0) && (v != vp);
  } else {
    sym  = 0;                       // blank
    skip = false;
  }
  const int sm2 = (tid >= 2) ? tid - 2 : 0;   // clamped: avoid LDS underflow

  const float* gbase   = logits + (size_t)b * TT * VV + sym;  // stride VV per t
  const float* lsebase = lse + b * TT;

  // ---- alpha0 (t = 0) ----
  float lse0 = lsebase[0];
  alpha[0][tid] = (tid <= 1) ? (gbase[0] - lse0) : NEGV;
  if (tid == 0) alpha[0][512] = NEGV;

  // ---- prefetch prologue: t = 1 .. DEPTH ----
  float pf[DEPTH], pl[DEPTH];
  #pragma unroll
  for (int d = 0; d < DEPTH; ++d) {
    int t = 1 + d; if (t > TT - 1) t = TT - 1;
    pf[d] = gbase[(size_t)t * VV];
    pl[d] = lsebase[t];
  }
  __syncthreads();

  // ---- main scan: t = 1 .. T-1 (999 steps) ----
  int p = 0;
  for (int tb = 1; tb < TT; tb += DEPTH) {
    #pragma unroll
    for (int d = 0; d < DEPTH; ++d) {
      int t = tb + d;
      if (t < TT) {                      // uniform across block
        float lp = pf[d] - pl[d];
        // issue prefetch for t+DEPTH (clamped; harmless duplicate at tail)
        int tf = t + DEPTH; if (tf > TT - 1) tf = TT - 1;
        pf[d] = gbase[(size_t)tf * VV];
        pl[d] = lsebase[tf];

        float a  = alpha[p][tid];
        float a1 = (tid >= 1) ? alpha[p][tid - 1] : NEGV;
        float a2 = skip ? alpha[p][sm2] : NEGV;
        float m  = fmaxf(a, fmaxf(a1, a2));
        float sm = __expf(a - m) + __expf(a1 - m) + __expf(a2 - m);
        alpha[p ^ 1][tid] = m + __logf(sm) + lp;

        if (tid == 0) {                  // extra state s = 512 (blank)
          float c0 = alpha[p][512];
          float c1 = alpha[p][511];
          float cm = fmaxf(c0, c1);
          float cs = __expf(c0 - cm) + __expf(c1 - cm) + __expf(NEGV - cm);
          alpha[p ^ 1][512] = cm + __logf(cs) + lp;  // lp is blank lp for tid 0
        }
        __syncthreads();
        p ^= 1;
      }
    }
  }

  // ---- readout ----
  if (tid == 0) {
    int len = nzcnt[0] + nzcnt[1] + nzcnt[2] + nzcnt[3];
    int eb  = 2 * len;
    int el  = (2 * len - 1 > 0) ? (2 * len - 1) : 0;
    float v1 = alpha[p][eb];
    float v2 = alpha[p][el];
    float m  = fmaxf(v1, v2);
    out[b] = -(m + __logf(__expf(v1 - m) + __expf(v2 - m)));
  }
}

// ---------------------------------------------------------------------------
extern "C" void kernel_launch(void* const* d_in, const int* in_sizes, int n_in,
                              void* d_out, int out_size, void* d_ws, size_t ws_size,
                              hipStream_t stream) {
  const float* logits = (const float*)d_in[0];   // [B,T,V] fp32
  const int*   labels = (const int*)d_in[1];     // [B,L] int32 (0 = pad/blank)
  float* out = (float*)d_out;                    // [B] fp32
  float* lse = (float*)d_ws;                     // B*T floats = 256 KB

  ctc_lse_kernel<<<(BB * TT) / 4, 256, 0, stream>>>(logits, lse);
  ctc_dp_kernel<<<BB, 512, 0, stream>>>(logits, labels, lse, out);
}